// Round 14
// baseline (466.412 us; speedup 1.0000x reference)
//
#include <hip/hip_runtime.h>
#include <hip/hip_bf16.h>

// GAT (3 layers) + MLP head. N=50000, E=800000 (+N self loops), D=128, H=256, C=6.
// Round 14: single-pass aggregate. Softmax is shift-invariant, so the true
// per-segment max is replaced by an upper bound leaky(max_all(avs)+avd[w])
// (avs spread ~±7 << 88, no underflow risk; ratios exact). Pass 1 (re-walk +
// two wave reductions + LDS) deleted. New shape: 16-lane group per node,
// one loop over edges (csrc -> avs -> exp -> half8 row FMA), full-row
// coalesced store, no shuffles/LDS. max_all(avs) fused into k_mfma_gat
// (one CAS-max per wave); mmax[3] initialized in k_prep.

typedef _Float16 h4 __attribute__((ext_vector_type(4)));
typedef _Float16 half8 __attribute__((ext_vector_type(8)));
typedef float f32x4 __attribute__((ext_vector_type(4)));

#define LDA 136   // padded fp16 row stride for MFMA staging (gat kernel)

__device__ inline void atomicMaxFloat(float* addr, float val) {
    int* ai = (int*)addr;
    int old = atomicCAS(ai, 0, 0);    // atomic read (value only ever increases)
    while (val > __int_as_float(old)) {
        int assumed = old;
        old = atomicCAS(ai, assumed, __float_as_int(val));
        if (old == assumed) break;
    }
}

__global__ __launch_bounds__(256) void k_hist(const int* __restrict__ ei, int* __restrict__ deg,
                                              int* __restrict__ rank, int E_, int N_) {
    int e = blockIdx.x * 256 + threadIdx.x;
    int total = E_ + N_;
    if (e >= total) return;
    int d = (e < E_) ? ei[E_ + e] : (e - E_);
    rank[e] = atomicAdd(&deg[d], 1);
}

__device__ inline int block_incl_scan(int v, int* wsum) {
    int lane = threadIdx.x & 63, wid = threadIdx.x >> 6;
    #pragma unroll
    for (int d = 1; d < 64; d <<= 1) {
        int t = __shfl_up(v, d);
        if (lane >= d) v += t;
    }
    if (lane == 63) wsum[wid] = v;
    __syncthreads();
    if (wid == 0 && lane < 4) {
        int s = wsum[lane];
        #pragma unroll
        for (int d = 1; d < 4; d <<= 1) {
            int t = __shfl_up(s, d);
            if (lane >= d) s += t;
        }
        wsum[lane] = s;
    }
    __syncthreads();
    if (wid > 0) v += wsum[wid - 1];
    return v;
}

__global__ __launch_bounds__(256) void k_bsum(const int* __restrict__ deg, int* __restrict__ bsum, int n) {
    __shared__ int wsum[4];
    int i = blockIdx.x * 256 + threadIdx.x;
    int v = (i < n) ? deg[i] : 0;
    int lane = threadIdx.x & 63, wid = threadIdx.x >> 6;
    #pragma unroll
    for (int d = 32; d > 0; d >>= 1) v += __shfl_down(v, d);
    if (lane == 0) wsum[wid] = v;
    __syncthreads();
    if (threadIdx.x == 0) bsum[blockIdx.x] = wsum[0] + wsum[1] + wsum[2] + wsum[3];
}

__global__ __launch_bounds__(256) void k_scanb(int* __restrict__ bsum, int nb) {
    __shared__ int wsum[4];
    int i = threadIdx.x;
    int orig = (i < nb) ? bsum[i] : 0;
    int v = block_incl_scan(orig, wsum);
    if (i < nb) bsum[i] = v - orig;
}

__global__ __launch_bounds__(256) void k_off(const int* __restrict__ deg, const int* __restrict__ bsum,
                                             int* __restrict__ off, int n) {
    __shared__ int wsum[4];
    int i = blockIdx.x * 256 + threadIdx.x;
    int orig = (i < n) ? deg[i] : 0;
    int v = block_incl_scan(orig, wsum);
    int base = bsum[blockIdx.x];
    if (i < n) off[i] = base + v - orig;
    if (i == n - 1) off[n] = base + v;
}

__global__ __launch_bounds__(256) void k_scatter(const int* __restrict__ ei, const int* __restrict__ off,
                                                 const int* __restrict__ rank, int* __restrict__ csrc,
                                                 int E_, int N_) {
    int e = blockIdx.x * 256 + threadIdx.x;
    int total = E_ + N_;
    if (e >= total) return;
    int s, d;
    if (e < E_) { s = ei[e]; d = ei[E_ + e]; }
    else        { s = e - E_; d = e - E_; }
    csrc[off[d] + rank[e]] = s;
}

// fused prep: x->fp16, W0..W2 transpose->fp16, Wm1 transpose->fp16, mmax init
__global__ __launch_bounds__(256) void k_prep(const float* __restrict__ x, _Float16* __restrict__ xh,
        const float* __restrict__ W0, const float* __restrict__ W1, const float* __restrict__ W2,
        _Float16* __restrict__ Wt3, const float* __restrict__ Wm1, _Float16* __restrict__ Wm1t,
        float* __restrict__ mmax, int n4) {
    int i = blockIdx.x * 256 + threadIdx.x;
    if (blockIdx.x == 0 && threadIdx.x < 3) mmax[threadIdx.x] = -1e30f;
    if (i < n4) {
        float4 v = ((const float4*)x)[i];
        h4 o;
        o.x = (_Float16)v.x; o.y = (_Float16)v.y; o.z = (_Float16)v.z; o.w = (_Float16)v.w;
        ((h4*)xh)[i] = o;
        return;
    }
    int t = i - n4;
    if (t < 3 * 16384) {
        int seg = t >> 14;
        int j = t & 16383;
        const float* W = (seg == 0) ? W0 : (seg == 1) ? W1 : W2;
        int nn = j >> 7, k = j & 127;
        Wt3[t] = (_Float16)W[k * 128 + nn];
        return;
    }
    t -= 3 * 16384;
    if (t < 32768) {
        int nn = t >> 7, k = t & 127;
        Wm1t[t] = (_Float16)Wm1[k * 256 + nn];
    }
}

// Layer GEMM via MFMA: hh[M x 128](fp16) = A16[M x 128] @ W + fused alpha dots
// + global max(avs) via one CAS-max per wave.
__global__ __launch_bounds__(256, 3) void k_mfma_gat(const _Float16* __restrict__ A16,
        const _Float16* __restrict__ Wt, const float* __restrict__ asrc, const float* __restrict__ adst,
        _Float16* __restrict__ hh, float* __restrict__ avs, float* __restrict__ avd,
        float* __restrict__ mmax, int M) {
    __shared__ _Float16 As[64 * LDA];
    __shared__ _Float16 Bs[128 * LDA];
    int tid = threadIdx.x;
    int bm = blockIdx.x * 64;
    #pragma unroll
    for (int i = 0; i < 4; ++i) {
        int idx = i * 256 + tid;
        int row = idx >> 4, c16 = idx & 15;
        int gr = bm + row;
        uint4 v = make_uint4(0u, 0u, 0u, 0u);
        if (gr < M) v = *(const uint4*)(A16 + (size_t)gr * 128 + c16 * 8);
        *(uint4*)&As[row * LDA + c16 * 8] = v;
    }
    #pragma unroll
    for (int i = 0; i < 8; ++i) {
        int idx = i * 256 + tid;
        int row = idx >> 4, c16 = idx & 15;
        *(uint4*)&Bs[row * LDA + c16 * 8] = *(const uint4*)(Wt + (size_t)row * 128 + c16 * 8);
    }
    __syncthreads();
    int w = tid >> 6, l = tid & 63;
    int quad = l >> 4, cl = l & 15;
    f32x4 acc[8] = {};
    const _Float16* ap = &As[(w * 16 + cl) * LDA + quad * 8];
    #pragma unroll
    for (int kt = 0; kt < 4; ++kt) {
        half8 a = *(const half8*)(ap + kt * 32);
        #pragma unroll
        for (int ct = 0; ct < 8; ++ct) {
            half8 b = *(const half8*)&Bs[(ct * 16 + cl) * LDA + kt * 32 + quad * 8];
            acc[ct] = __builtin_amdgcn_mfma_f32_16x16x32_f16(a, b, acc[ct], 0, 0, 0);
        }
    }
    float sa[8], da[8];
    #pragma unroll
    for (int ct = 0; ct < 8; ++ct) { sa[ct] = asrc[ct * 16 + cl]; da[ct] = adst[ct * 16 + cl]; }
    float pmax = -1e30f;
    #pragma unroll
    for (int r = 0; r < 4; ++r) {
        int row = bm + w * 16 + quad * 4 + r;
        bool ok = row < M;
        float ps = 0.f, pd = 0.f;
        #pragma unroll
        for (int ct = 0; ct < 8; ++ct) {
            float v = acc[ct][r];
            if (ok) hh[(size_t)row * 128 + ct * 16 + cl] = (_Float16)v;
            ps += v * sa[ct];
            pd += v * da[ct];
        }
        #pragma unroll
        for (int msk = 1; msk <= 8; msk <<= 1) { ps += __shfl_xor(ps, msk); pd += __shfl_xor(pd, msk); }
        if (ok) pmax = fmaxf(pmax, ps);
        if (cl == 0 && ok) { avs[row] = ps; avd[row] = pd; }
    }
    pmax = fmaxf(pmax, __shfl_xor(pmax, 16));
    pmax = fmaxf(pmax, __shfl_xor(pmax, 32));
    if (l == 0) atomicMaxFloat(mmax, pmax);
}

// Fused MLP, acc[8]-only (proven spill-free): out = relu(A16@Wm1+bm1)@Wm2+bm2.
__global__ __launch_bounds__(256) void k_mfma_mlp(const _Float16* __restrict__ A16,
        const _Float16* __restrict__ Wt, const float* __restrict__ bias,
        const float* __restrict__ W2, const float* __restrict__ b2,
        float* __restrict__ out, int M) {
    __shared__ float W2s[256 * 6];
    __shared__ float bss[256];
    __shared__ float comb[4][16][6];
    int tid = threadIdx.x;
    #pragma unroll
    for (int i = 0; i < 6; ++i) W2s[i * 256 + tid] = W2[i * 256 + tid];
    bss[tid] = bias[tid];
    __syncthreads();
    int w = tid >> 6, l = tid & 63;
    int quad = l >> 4, cl = l & 15;
    int rg = w >> 1;
    int ch = w & 1;
    int bm = blockIdx.x * 32 + rg * 16;
    int arow = bm + cl;
    int arc = (arow < M) ? arow : (M - 1);
    const _Float16* ap = A16 + (size_t)arc * 128 + quad * 8;
    f32x4 acc[8];
    #pragma unroll
    for (int i = 0; i < 8; ++i) acc[i] = (f32x4){0.f, 0.f, 0.f, 0.f};
    #pragma unroll
    for (int kt = 0; kt < 4; ++kt) {
        half8 av = *(const half8*)(ap + kt * 32);
        const _Float16* bp = Wt + (size_t)(ch * 128 + cl) * 128 + kt * 32 + quad * 8;
        #pragma unroll
        for (int ct = 0; ct < 8; ++ct) {
            half8 bv = *(const half8*)(bp + (size_t)ct * 16 * 128);
            acc[ct] = __builtin_amdgcn_mfma_f32_16x16x32_f16(av, bv, acc[ct], 0, 0, 0);
        }
    }
    float pc[4][6] = {};
    #pragma unroll
    for (int ct = 0; ct < 8; ++ct) {
        int col = ch * 128 + ct * 16 + cl;
        float bb = bss[col];
        float w0 = W2s[col * 6 + 0], w1 = W2s[col * 6 + 1], w2v = W2s[col * 6 + 2];
        float w3 = W2s[col * 6 + 3], w4 = W2s[col * 6 + 4], w5 = W2s[col * 6 + 5];
        #pragma unroll
        for (int r = 0; r < 4; ++r) {
            float v = fmaxf(acc[ct][r] + bb, 0.f);
            pc[r][0] += v * w0; pc[r][1] += v * w1; pc[r][2] += v * w2v;
            pc[r][3] += v * w3; pc[r][4] += v * w4; pc[r][5] += v * w5;
        }
    }
    #pragma unroll
    for (int r = 0; r < 4; ++r) {
        #pragma unroll
        for (int msk = 1; msk <= 8; msk <<= 1) {
            #pragma unroll
            for (int c = 0; c < 6; ++c) pc[r][c] += __shfl_xor(pc[r][c], msk);
        }
        if (cl == 0) {
            #pragma unroll
            for (int c = 0; c < 6; ++c) comb[w][quad * 4 + r][c] = pc[r][c];
        }
    }
    __syncthreads();
    if (tid < 192) {
        int rgg = tid / 96;
        int rem = tid % 96;
        int rr = rem / 6, c = rem % 6;
        int row = blockIdx.x * 32 + rgg * 16 + rr;
        if (row < M)
            out[(size_t)row * 6 + c] = comb[rgg * 2][rr][c] + comb[rgg * 2 + 1][rr][c] + b2[c];
    }
}

// Single-pass aggregate: 16-lane group per dst node. bound = leaky(mmax+avd[w])
// upper-bounds the segment max (softmax shift-invariant -> ratios exact).
// Loop: csrc -> avs -> exp(sc-bound) -> half8 row FMA. No shuffles, no LDS.
__global__ __launch_bounds__(256) void k_aggregate(const _Float16* __restrict__ hh, const int* __restrict__ off,
                                                   const int* __restrict__ csrc, const float* __restrict__ avs,
                                                   const float* __restrict__ avd, const float* __restrict__ mmax,
                                                   const float* __restrict__ bias, _Float16* __restrict__ outh,
                                                   int n) {
    int g = (blockIdx.x * 256 + threadIdx.x) >> 4;   // node
    int gl = threadIdx.x & 15;                        // feature octet
    if (g >= n) return;
    int beg = off[g], end = off[g + 1];
    float adn = avd[g];
    float t = mmax[0] + adn;
    float bnd = (t < 0.f) ? 0.2f * t : t;            // >= true segment max
    float accf[8] = {};
    float ssum = 0.f;
    int j = beg;
    for (; j + 3 < end; j += 4) {
        int s0 = csrc[j], s1 = csrc[j + 1], s2 = csrc[j + 2], s3 = csrc[j + 3];
        half8 v0 = *((const half8*)(hh + (size_t)s0 * 128) + gl);
        half8 v1 = *((const half8*)(hh + (size_t)s1 * 128) + gl);
        half8 v2 = *((const half8*)(hh + (size_t)s2 * 128) + gl);
        half8 v3 = *((const half8*)(hh + (size_t)s3 * 128) + gl);
        float sc0 = avs[s0] + adn; sc0 = (sc0 < 0.f) ? 0.2f * sc0 : sc0;
        float sc1 = avs[s1] + adn; sc1 = (sc1 < 0.f) ? 0.2f * sc1 : sc1;
        float sc2 = avs[s2] + adn; sc2 = (sc2 < 0.f) ? 0.2f * sc2 : sc2;
        float sc3 = avs[s3] + adn; sc3 = (sc3 < 0.f) ? 0.2f * sc3 : sc3;
        float e0 = __expf(sc0 - bnd), e1 = __expf(sc1 - bnd);
        float e2 = __expf(sc2 - bnd), e3 = __expf(sc3 - bnd);
        ssum += (e0 + e1) + (e2 + e3);
        #pragma unroll
        for (int f = 0; f < 8; ++f)
            accf[f] += (e0 * (float)v0[f] + e1 * (float)v1[f])
                     + (e2 * (float)v2[f] + e3 * (float)v3[f]);
    }
    for (; j < end; ++j) {
        int s0 = csrc[j];
        half8 v0 = *((const half8*)(hh + (size_t)s0 * 128) + gl);
        float sc0 = avs[s0] + adn; sc0 = (sc0 < 0.f) ? 0.2f * sc0 : sc0;
        float e0 = __expf(sc0 - bnd);
        ssum += e0;
        #pragma unroll
        for (int f = 0; f < 8; ++f) accf[f] += e0 * (float)v0[f];
    }
    float inv = 1.f / ssum;
    float4 b0 = ((const float4*)bias)[gl * 2];
    float4 b1 = ((const float4*)bias)[gl * 2 + 1];
    half8 o;
    o[0] = (_Float16)fmaxf(accf[0] * inv + b0.x, 0.f);
    o[1] = (_Float16)fmaxf(accf[1] * inv + b0.y, 0.f);
    o[2] = (_Float16)fmaxf(accf[2] * inv + b0.z, 0.f);
    o[3] = (_Float16)fmaxf(accf[3] * inv + b0.w, 0.f);
    o[4] = (_Float16)fmaxf(accf[4] * inv + b1.x, 0.f);
    o[5] = (_Float16)fmaxf(accf[5] * inv + b1.y, 0.f);
    o[6] = (_Float16)fmaxf(accf[6] * inv + b1.z, 0.f);
    o[7] = (_Float16)fmaxf(accf[7] * inv + b1.w, 0.f);
    *((half8*)(outh + (size_t)g * 128) + gl) = o;
}

extern "C" void kernel_launch(void* const* d_in, const int* in_sizes, int n_in,
                              void* d_out, int out_size, void* d_ws, size_t ws_size,
                              hipStream_t stream) {
    const float* x   = (const float*)d_in[0];
    const int*   ei  = (const int*)d_in[1];
    const float* W[3]    = {(const float*)d_in[2], (const float*)d_in[6], (const float*)d_in[10]};
    const float* bL[3]   = {(const float*)d_in[3], (const float*)d_in[7], (const float*)d_in[11]};
    const float* asr[3]  = {(const float*)d_in[4], (const float*)d_in[8], (const float*)d_in[12]};
    const float* ads[3]  = {(const float*)d_in[5], (const float*)d_in[9], (const float*)d_in[13]};
    const float* Wm1 = (const float*)d_in[14];
    const float* bm1 = (const float*)d_in[15];
    const float* Wm2 = (const float*)d_in[16];
    const float* bm2 = (const float*)d_in[17];
    float* out = (float*)d_out;

    const int N_ = in_sizes[0] / 128;
    const int E_ = in_sizes[1] / 2;
    const int TOT = E_ + N_;
    const int NB = (N_ + 255) / 256;

    char* p = (char*)d_ws;
    auto alloc = [&](size_t bytes) { void* r = (void*)p; p += (bytes + 255) & ~(size_t)255; return r; };
    size_t npad = ((size_t)N_ * 4 + 255) & ~(size_t)255;
    int*   deg  = (int*)alloc(npad);
    int*   off  = (int*)alloc((size_t)(N_ + 1) * 4);
    int*   bsum = (int*)alloc((size_t)(NB + 1) * 4);
    int*   rank = (int*)alloc((size_t)TOT * 4);
    int*   csrc = (int*)alloc((size_t)TOT * 4);
    float* avs  = (float*)alloc((size_t)N_ * 4);
    float* avd  = (float*)alloc((size_t)N_ * 4);
    float* mmax = (float*)alloc(256);
    _Float16* Wt3  = (_Float16*)alloc(3 * 16384 * 2);
    _Float16* Wm1t = (_Float16*)alloc(32768 * 2);
    _Float16* xh   = (_Float16*)alloc((size_t)N_ * 128 * 2);
    _Float16* agg  = (_Float16*)alloc((size_t)N_ * 128 * 2);
    _Float16* hh   = (_Float16*)alloc((size_t)N_ * 128 * 2);

    // ---- CSR build + prep ----
    hipMemsetAsync(deg, 0, npad, stream);
    k_hist<<<(TOT + 255) / 256, 256, 0, stream>>>(ei, deg, rank, E_, N_);
    k_bsum<<<NB, 256, 0, stream>>>(deg, bsum, N_);
    k_scanb<<<1, 256, 0, stream>>>(bsum, NB);
    k_off<<<NB, 256, 0, stream>>>(deg, bsum, off, N_);
    k_scatter<<<(TOT + 255) / 256, 256, 0, stream>>>(ei, off, rank, csrc, E_, N_);
    int n4 = N_ * 32;
    int prep_items = n4 + 3 * 16384 + 32768;
    k_prep<<<(prep_items + 255) / 256, 256, 0, stream>>>(x, xh, W[0], W[1], W[2], Wt3, Wm1, Wm1t,
                                                         mmax, n4);

    const int gat_blocks = (N_ + 63) / 64;
    const int agg_blocks = (N_ + 15) / 16;

    // ---- 3 GAT layers ----
    const _Float16* cur_in = xh;
    for (int l = 0; l < 3; ++l) {
        k_mfma_gat<<<gat_blocks, 256, 0, stream>>>(cur_in, Wt3 + l * 16384, asr[l], ads[l],
                                                   hh, avs, avd, mmax + l, N_);
        k_aggregate<<<agg_blocks, 256, 0, stream>>>(hh, off, csrc, avs, avd, mmax + l,
                                                    bL[l], agg, N_);
        cur_in = agg;
    }

    // ---- fused MLP head ----
    k_mfma_mlp<<<(N_ + 31) / 32, 256, 0, stream>>>(agg, Wm1t, bm1, Wm2, bm2, out, N_);
}

// Round 15
// 352.372 us; speedup vs baseline: 1.3236x; 1.3236x over previous
//
#include <hip/hip_runtime.h>
#include <hip/hip_bf16.h>

// GAT (3 layers) + MLP head. N=50000, E=800000 (+N self loops), D=128, H=256, C=6.
// Round 15: R14's CAS-loop float-max (3128 spinning waves on ONE address ->
// gat 20->78us, VALUBusy 2%) replaced by a retry-free hardware atomicMax(int)
// on an order-preserving encoding (b<0 ? b^0x7FFFFFFF : b), ONE per block via
// a 16B LDS wave-max combine. Single-pass aggregate from R14 kept (it was the
// win: ~44 -> ~20us/layer).

typedef _Float16 h4 __attribute__((ext_vector_type(4)));
typedef _Float16 half8 __attribute__((ext_vector_type(8)));
typedef float f32x4 __attribute__((ext_vector_type(4)));

#define LDA 136   // padded fp16 row stride for MFMA staging (gat kernel)

__device__ inline int enc_f32(float f) {
    int b = __float_as_int(f);
    return (b < 0) ? (b ^ 0x7FFFFFFF) : b;
}
__device__ inline float dec_f32(int i) {
    return __int_as_float((i < 0) ? (i ^ 0x7FFFFFFF) : i);
}

__global__ __launch_bounds__(256) void k_hist(const int* __restrict__ ei, int* __restrict__ deg,
                                              int* __restrict__ rank, int E_, int N_) {
    int e = blockIdx.x * 256 + threadIdx.x;
    int total = E_ + N_;
    if (e >= total) return;
    int d = (e < E_) ? ei[E_ + e] : (e - E_);
    rank[e] = atomicAdd(&deg[d], 1);
}

__device__ inline int block_incl_scan(int v, int* wsum) {
    int lane = threadIdx.x & 63, wid = threadIdx.x >> 6;
    #pragma unroll
    for (int d = 1; d < 64; d <<= 1) {
        int t = __shfl_up(v, d);
        if (lane >= d) v += t;
    }
    if (lane == 63) wsum[wid] = v;
    __syncthreads();
    if (wid == 0 && lane < 4) {
        int s = wsum[lane];
        #pragma unroll
        for (int d = 1; d < 4; d <<= 1) {
            int t = __shfl_up(s, d);
            if (lane >= d) s += t;
        }
        wsum[lane] = s;
    }
    __syncthreads();
    if (wid > 0) v += wsum[wid - 1];
    return v;
}

__global__ __launch_bounds__(256) void k_bsum(const int* __restrict__ deg, int* __restrict__ bsum, int n) {
    __shared__ int wsum[4];
    int i = blockIdx.x * 256 + threadIdx.x;
    int v = (i < n) ? deg[i] : 0;
    int lane = threadIdx.x & 63, wid = threadIdx.x >> 6;
    #pragma unroll
    for (int d = 32; d > 0; d >>= 1) v += __shfl_down(v, d);
    if (lane == 0) wsum[wid] = v;
    __syncthreads();
    if (threadIdx.x == 0) bsum[blockIdx.x] = wsum[0] + wsum[1] + wsum[2] + wsum[3];
}

__global__ __launch_bounds__(256) void k_scanb(int* __restrict__ bsum, int nb) {
    __shared__ int wsum[4];
    int i = threadIdx.x;
    int orig = (i < nb) ? bsum[i] : 0;
    int v = block_incl_scan(orig, wsum);
    if (i < nb) bsum[i] = v - orig;
}

__global__ __launch_bounds__(256) void k_off(const int* __restrict__ deg, const int* __restrict__ bsum,
                                             int* __restrict__ off, int n) {
    __shared__ int wsum[4];
    int i = blockIdx.x * 256 + threadIdx.x;
    int orig = (i < n) ? deg[i] : 0;
    int v = block_incl_scan(orig, wsum);
    int base = bsum[blockIdx.x];
    if (i < n) off[i] = base + v - orig;
    if (i == n - 1) off[n] = base + v;
}

__global__ __launch_bounds__(256) void k_scatter(const int* __restrict__ ei, const int* __restrict__ off,
                                                 const int* __restrict__ rank, int* __restrict__ csrc,
                                                 int E_, int N_) {
    int e = blockIdx.x * 256 + threadIdx.x;
    int total = E_ + N_;
    if (e >= total) return;
    int s, d;
    if (e < E_) { s = ei[e]; d = ei[E_ + e]; }
    else        { s = e - E_; d = e - E_; }
    csrc[off[d] + rank[e]] = s;
}

// fused prep: x->fp16, W0..W2 transpose->fp16, Wm1 transpose->fp16, mmax init
__global__ __launch_bounds__(256) void k_prep(const float* __restrict__ x, _Float16* __restrict__ xh,
        const float* __restrict__ W0, const float* __restrict__ W1, const float* __restrict__ W2,
        _Float16* __restrict__ Wt3, const float* __restrict__ Wm1, _Float16* __restrict__ Wm1t,
        int* __restrict__ mmax, int n4) {
    int i = blockIdx.x * 256 + threadIdx.x;
    if (blockIdx.x == 0 && threadIdx.x < 3) mmax[threadIdx.x] = 0x80000000;  // encoded -inf
    if (i < n4) {
        float4 v = ((const float4*)x)[i];
        h4 o;
        o.x = (_Float16)v.x; o.y = (_Float16)v.y; o.z = (_Float16)v.z; o.w = (_Float16)v.w;
        ((h4*)xh)[i] = o;
        return;
    }
    int t = i - n4;
    if (t < 3 * 16384) {
        int seg = t >> 14;
        int j = t & 16383;
        const float* W = (seg == 0) ? W0 : (seg == 1) ? W1 : W2;
        int nn = j >> 7, k = j & 127;
        Wt3[t] = (_Float16)W[k * 128 + nn];
        return;
    }
    t -= 3 * 16384;
    if (t < 32768) {
        int nn = t >> 7, k = t & 127;
        Wm1t[t] = (_Float16)Wm1[k * 256 + nn];
    }
}

// Layer GEMM via MFMA: hh[M x 128](fp16) = A16[M x 128] @ W + fused alpha dots
// + global max(avs): LDS wave-max combine, ONE hardware atomicMax per block.
__global__ __launch_bounds__(256, 3) void k_mfma_gat(const _Float16* __restrict__ A16,
        const _Float16* __restrict__ Wt, const float* __restrict__ asrc, const float* __restrict__ adst,
        _Float16* __restrict__ hh, float* __restrict__ avs, float* __restrict__ avd,
        int* __restrict__ mmax, int M) {
    __shared__ _Float16 As[64 * LDA];
    __shared__ _Float16 Bs[128 * LDA];
    __shared__ int wmaxs[4];
    int tid = threadIdx.x;
    int bm = blockIdx.x * 64;
    #pragma unroll
    for (int i = 0; i < 4; ++i) {
        int idx = i * 256 + tid;
        int row = idx >> 4, c16 = idx & 15;
        int gr = bm + row;
        uint4 v = make_uint4(0u, 0u, 0u, 0u);
        if (gr < M) v = *(const uint4*)(A16 + (size_t)gr * 128 + c16 * 8);
        *(uint4*)&As[row * LDA + c16 * 8] = v;
    }
    #pragma unroll
    for (int i = 0; i < 8; ++i) {
        int idx = i * 256 + tid;
        int row = idx >> 4, c16 = idx & 15;
        *(uint4*)&Bs[row * LDA + c16 * 8] = *(const uint4*)(Wt + (size_t)row * 128 + c16 * 8);
    }
    __syncthreads();
    int w = tid >> 6, l = tid & 63;
    int quad = l >> 4, cl = l & 15;
    f32x4 acc[8] = {};
    const _Float16* ap = &As[(w * 16 + cl) * LDA + quad * 8];
    #pragma unroll
    for (int kt = 0; kt < 4; ++kt) {
        half8 a = *(const half8*)(ap + kt * 32);
        #pragma unroll
        for (int ct = 0; ct < 8; ++ct) {
            half8 b = *(const half8*)&Bs[(ct * 16 + cl) * LDA + kt * 32 + quad * 8];
            acc[ct] = __builtin_amdgcn_mfma_f32_16x16x32_f16(a, b, acc[ct], 0, 0, 0);
        }
    }
    float sa[8], da[8];
    #pragma unroll
    for (int ct = 0; ct < 8; ++ct) { sa[ct] = asrc[ct * 16 + cl]; da[ct] = adst[ct * 16 + cl]; }
    float pmax = -1e30f;
    #pragma unroll
    for (int r = 0; r < 4; ++r) {
        int row = bm + w * 16 + quad * 4 + r;
        bool ok = row < M;
        float ps = 0.f, pd = 0.f;
        #pragma unroll
        for (int ct = 0; ct < 8; ++ct) {
            float v = acc[ct][r];
            if (ok) hh[(size_t)row * 128 + ct * 16 + cl] = (_Float16)v;
            ps += v * sa[ct];
            pd += v * da[ct];
        }
        #pragma unroll
        for (int msk = 1; msk <= 8; msk <<= 1) { ps += __shfl_xor(ps, msk); pd += __shfl_xor(pd, msk); }
        if (ok) pmax = fmaxf(pmax, ps);
        if (cl == 0 && ok) { avs[row] = ps; avd[row] = pd; }
    }
    pmax = fmaxf(pmax, __shfl_xor(pmax, 16));
    pmax = fmaxf(pmax, __shfl_xor(pmax, 32));
    if (l == 0) wmaxs[w] = enc_f32(pmax);
    __syncthreads();
    if (tid == 0) {
        int m01 = max(wmaxs[0], wmaxs[1]);
        int m23 = max(wmaxs[2], wmaxs[3]);
        atomicMax(mmax, max(m01, m23));
    }
}

// Fused MLP, acc[8]-only (proven spill-free): out = relu(A16@Wm1+bm1)@Wm2+bm2.
__global__ __launch_bounds__(256) void k_mfma_mlp(const _Float16* __restrict__ A16,
        const _Float16* __restrict__ Wt, const float* __restrict__ bias,
        const float* __restrict__ W2, const float* __restrict__ b2,
        float* __restrict__ out, int M) {
    __shared__ float W2s[256 * 6];
    __shared__ float bss[256];
    __shared__ float comb[4][16][6];
    int tid = threadIdx.x;
    #pragma unroll
    for (int i = 0; i < 6; ++i) W2s[i * 256 + tid] = W2[i * 256 + tid];
    bss[tid] = bias[tid];
    __syncthreads();
    int w = tid >> 6, l = tid & 63;
    int quad = l >> 4, cl = l & 15;
    int rg = w >> 1;
    int ch = w & 1;
    int bm = blockIdx.x * 32 + rg * 16;
    int arow = bm + cl;
    int arc = (arow < M) ? arow : (M - 1);
    const _Float16* ap = A16 + (size_t)arc * 128 + quad * 8;
    f32x4 acc[8];
    #pragma unroll
    for (int i = 0; i < 8; ++i) acc[i] = (f32x4){0.f, 0.f, 0.f, 0.f};
    #pragma unroll
    for (int kt = 0; kt < 4; ++kt) {
        half8 av = *(const half8*)(ap + kt * 32);
        const _Float16* bp = Wt + (size_t)(ch * 128 + cl) * 128 + kt * 32 + quad * 8;
        #pragma unroll
        for (int ct = 0; ct < 8; ++ct) {
            half8 bv = *(const half8*)(bp + (size_t)ct * 16 * 128);
            acc[ct] = __builtin_amdgcn_mfma_f32_16x16x32_f16(av, bv, acc[ct], 0, 0, 0);
        }
    }
    float pc[4][6] = {};
    #pragma unroll
    for (int ct = 0; ct < 8; ++ct) {
        int col = ch * 128 + ct * 16 + cl;
        float bb = bss[col];
        float w0 = W2s[col * 6 + 0], w1 = W2s[col * 6 + 1], w2v = W2s[col * 6 + 2];
        float w3 = W2s[col * 6 + 3], w4 = W2s[col * 6 + 4], w5 = W2s[col * 6 + 5];
        #pragma unroll
        for (int r = 0; r < 4; ++r) {
            float v = fmaxf(acc[ct][r] + bb, 0.f);
            pc[r][0] += v * w0; pc[r][1] += v * w1; pc[r][2] += v * w2v;
            pc[r][3] += v * w3; pc[r][4] += v * w4; pc[r][5] += v * w5;
        }
    }
    #pragma unroll
    for (int r = 0; r < 4; ++r) {
        #pragma unroll
        for (int msk = 1; msk <= 8; msk <<= 1) {
            #pragma unroll
            for (int c = 0; c < 6; ++c) pc[r][c] += __shfl_xor(pc[r][c], msk);
        }
        if (cl == 0) {
            #pragma unroll
            for (int c = 0; c < 6; ++c) comb[w][quad * 4 + r][c] = pc[r][c];
        }
    }
    __syncthreads();
    if (tid < 192) {
        int rgg = tid / 96;
        int rem = tid % 96;
        int rr = rem / 6, c = rem % 6;
        int row = blockIdx.x * 32 + rgg * 16 + rr;
        if (row < M)
            out[(size_t)row * 6 + c] = comb[rgg * 2][rr][c] + comb[rgg * 2 + 1][rr][c] + b2[c];
    }
}

// Single-pass aggregate: 16-lane group per dst node. bound = leaky(mmax+avd[g])
// upper-bounds the segment max (softmax shift-invariant -> ratios exact).
__global__ __launch_bounds__(256) void k_aggregate(const _Float16* __restrict__ hh, const int* __restrict__ off,
                                                   const int* __restrict__ csrc, const float* __restrict__ avs,
                                                   const float* __restrict__ avd, const int* __restrict__ mmax,
                                                   const float* __restrict__ bias, _Float16* __restrict__ outh,
                                                   int n) {
    int g = (blockIdx.x * 256 + threadIdx.x) >> 4;   // node
    int gl = threadIdx.x & 15;                        // feature octet
    if (g >= n) return;
    int beg = off[g], end = off[g + 1];
    float adn = avd[g];
    float t = dec_f32(mmax[0]) + adn;
    float bnd = (t < 0.f) ? 0.2f * t : t;            // >= true segment max
    float accf[8] = {};
    float ssum = 0.f;
    int j = beg;
    for (; j + 3 < end; j += 4) {
        int s0 = csrc[j], s1 = csrc[j + 1], s2 = csrc[j + 2], s3 = csrc[j + 3];
        half8 v0 = *((const half8*)(hh + (size_t)s0 * 128) + gl);
        half8 v1 = *((const half8*)(hh + (size_t)s1 * 128) + gl);
        half8 v2 = *((const half8*)(hh + (size_t)s2 * 128) + gl);
        half8 v3 = *((const half8*)(hh + (size_t)s3 * 128) + gl);
        float sc0 = avs[s0] + adn; sc0 = (sc0 < 0.f) ? 0.2f * sc0 : sc0;
        float sc1 = avs[s1] + adn; sc1 = (sc1 < 0.f) ? 0.2f * sc1 : sc1;
        float sc2 = avs[s2] + adn; sc2 = (sc2 < 0.f) ? 0.2f * sc2 : sc2;
        float sc3 = avs[s3] + adn; sc3 = (sc3 < 0.f) ? 0.2f * sc3 : sc3;
        float e0 = __expf(sc0 - bnd), e1 = __expf(sc1 - bnd);
        float e2 = __expf(sc2 - bnd), e3 = __expf(sc3 - bnd);
        ssum += (e0 + e1) + (e2 + e3);
        #pragma unroll
        for (int f = 0; f < 8; ++f)
            accf[f] += (e0 * (float)v0[f] + e1 * (float)v1[f])
                     + (e2 * (float)v2[f] + e3 * (float)v3[f]);
    }
    for (; j < end; ++j) {
        int s0 = csrc[j];
        half8 v0 = *((const half8*)(hh + (size_t)s0 * 128) + gl);
        float sc0 = avs[s0] + adn; sc0 = (sc0 < 0.f) ? 0.2f * sc0 : sc0;
        float e0 = __expf(sc0 - bnd);
        ssum += e0;
        #pragma unroll
        for (int f = 0; f < 8; ++f) accf[f] += e0 * (float)v0[f];
    }
    float inv = 1.f / ssum;
    float4 b0 = ((const float4*)bias)[gl * 2];
    float4 b1 = ((const float4*)bias)[gl * 2 + 1];
    half8 o;
    o[0] = (_Float16)fmaxf(accf[0] * inv + b0.x, 0.f);
    o[1] = (_Float16)fmaxf(accf[1] * inv + b0.y, 0.f);
    o[2] = (_Float16)fmaxf(accf[2] * inv + b0.z, 0.f);
    o[3] = (_Float16)fmaxf(accf[3] * inv + b0.w, 0.f);
    o[4] = (_Float16)fmaxf(accf[4] * inv + b1.x, 0.f);
    o[5] = (_Float16)fmaxf(accf[5] * inv + b1.y, 0.f);
    o[6] = (_Float16)fmaxf(accf[6] * inv + b1.z, 0.f);
    o[7] = (_Float16)fmaxf(accf[7] * inv + b1.w, 0.f);
    *((half8*)(outh + (size_t)g * 128) + gl) = o;
}

extern "C" void kernel_launch(void* const* d_in, const int* in_sizes, int n_in,
                              void* d_out, int out_size, void* d_ws, size_t ws_size,
                              hipStream_t stream) {
    const float* x   = (const float*)d_in[0];
    const int*   ei  = (const int*)d_in[1];
    const float* W[3]    = {(const float*)d_in[2], (const float*)d_in[6], (const float*)d_in[10]};
    const float* bL[3]   = {(const float*)d_in[3], (const float*)d_in[7], (const float*)d_in[11]};
    const float* asr[3]  = {(const float*)d_in[4], (const float*)d_in[8], (const float*)d_in[12]};
    const float* ads[3]  = {(const float*)d_in[5], (const float*)d_in[9], (const float*)d_in[13]};
    const float* Wm1 = (const float*)d_in[14];
    const float* bm1 = (const float*)d_in[15];
    const float* Wm2 = (const float*)d_in[16];
    const float* bm2 = (const float*)d_in[17];
    float* out = (float*)d_out;

    const int N_ = in_sizes[0] / 128;
    const int E_ = in_sizes[1] / 2;
    const int TOT = E_ + N_;
    const int NB = (N_ + 255) / 256;

    char* p = (char*)d_ws;
    auto alloc = [&](size_t bytes) { void* r = (void*)p; p += (bytes + 255) & ~(size_t)255; return r; };
    size_t npad = ((size_t)N_ * 4 + 255) & ~(size_t)255;
    int*   deg  = (int*)alloc(npad);
    int*   off  = (int*)alloc((size_t)(N_ + 1) * 4);
    int*   bsum = (int*)alloc((size_t)(NB + 1) * 4);
    int*   rank = (int*)alloc((size_t)TOT * 4);
    int*   csrc = (int*)alloc((size_t)TOT * 4);
    float* avs  = (float*)alloc((size_t)N_ * 4);
    float* avd  = (float*)alloc((size_t)N_ * 4);
    int*   mmax = (int*)alloc(256);
    _Float16* Wt3  = (_Float16*)alloc(3 * 16384 * 2);
    _Float16* Wm1t = (_Float16*)alloc(32768 * 2);
    _Float16* xh   = (_Float16*)alloc((size_t)N_ * 128 * 2);
    _Float16* agg  = (_Float16*)alloc((size_t)N_ * 128 * 2);
    _Float16* hh   = (_Float16*)alloc((size_t)N_ * 128 * 2);

    // ---- CSR build + prep ----
    hipMemsetAsync(deg, 0, npad, stream);
    k_hist<<<(TOT + 255) / 256, 256, 0, stream>>>(ei, deg, rank, E_, N_);
    k_bsum<<<NB, 256, 0, stream>>>(deg, bsum, N_);
    k_scanb<<<1, 256, 0, stream>>>(bsum, NB);
    k_off<<<NB, 256, 0, stream>>>(deg, bsum, off, N_);
    k_scatter<<<(TOT + 255) / 256, 256, 0, stream>>>(ei, off, rank, csrc, E_, N_);
    int n4 = N_ * 32;
    int prep_items = n4 + 3 * 16384 + 32768;
    k_prep<<<(prep_items + 255) / 256, 256, 0, stream>>>(x, xh, W[0], W[1], W[2], Wt3, Wm1, Wm1t,
                                                         mmax, n4);

    const int gat_blocks = (N_ + 63) / 64;
    const int agg_blocks = (N_ + 15) / 16;

    // ---- 3 GAT layers ----
    const _Float16* cur_in = xh;
    for (int l = 0; l < 3; ++l) {
        k_mfma_gat<<<gat_blocks, 256, 0, stream>>>(cur_in, Wt3 + l * 16384, asr[l], ads[l],
                                                   hh, avs, avd, mmax + l, N_);
        k_aggregate<<<agg_blocks, 256, 0, stream>>>(hh, off, csrc, avs, avd, mmax + l,
                                                    bL[l], agg, N_);
        cur_in = agg;
    }

    // ---- fused MLP head ----
    k_mfma_mlp<<<(N_ + 31) / 32, 256, 0, stream>>>(agg, Wm1t, bm1, Wm2, bm2, out, N_);
}